// Round 12
// baseline (382.172 us; speedup 1.0000x reference)
//
#include <hip/hip_runtime.h>
#include <hip/hip_cooperative_groups.h>
#include <hip/hip_bf16.h>

namespace cg = cooperative_groups;

#define B_ 8
#define T_ 2048
#define D_ 256
#define S_ 2048
#define NBLK 2048   // exactly 8 blocks/CU * 256 CU co-resident

// Single cooperative kernel: phase1 dotcos (all blocks) -> grid.sync ->
// phase2 boundary (blocks 0..7, bit-identical to r8 k_boundary) -> grid.sync ->
// phase3 pool (all blocks, r8 k_pool wave-per-s body, 8 s per block).
__global__ __launch_bounds__(256, 8) void k_all(const float* __restrict__ fr,
                                                float* __restrict__ cosg,
                                                float* __restrict__ bcg,
                                                float* __restrict__ numfrg,
                                                float* __restrict__ out){
  cg::grid_group grid = cg::this_grid();
  __shared__ float sd[T_];
  __shared__ float sb[T_];
  __shared__ float smin[4], smax[4], swv[4];
  int tid = threadIdx.x;
  int lane = tid & 63, w = tid >> 6;
  int blk = blockIdx.x;

  // ---- phase 1: cos[b,t] (r8 k_dotcos, grid-stride over 16384 rows) ----
  {
    const float4* f4 = (const float4*)fr;
    #pragma unroll
    for (int rep = 0; rep < 2; ++rep){
      int p = blk * 4 + w + rep * 8192;          // p = b*T + t
      int t = p & (T_ - 1);
      float4 a = f4[(size_t)p * 64 + lane];
      float na = a.x*a.x + a.y*a.y + a.z*a.z + a.w*a.w;
      float nc = 0.0f, dt = 0.0f;
      if (t < T_ - 1){
        float4 c = f4[(size_t)(p + 1) * 64 + lane];
        nc = c.x*c.x + c.y*c.y + c.z*c.z + c.w*c.w;
        dt = a.x*c.x + a.y*c.y + a.z*c.z + a.w*c.w;
      }
      #pragma unroll
      for (int m = 32; m >= 1; m >>= 1){
        na += __shfl_xor(na, m, 64);
        nc += __shfl_xor(nc, m, 64);
        dt += __shfl_xor(dt, m, 64);
      }
      if (lane == 0 && t < T_ - 1)
        cosg[p] = dt / fmaxf(sqrtf(na) * sqrtf(nc), 1e-6f);
    }
  }
  grid.sync();

  // ---- phase 2: boundary chain for batch blk (blocks 0..7 only) ----
  if (blk < B_){
    int b = blk;
    const float* cG = cosg + b * T_;
    for (int t = tid; t < T_ - 1; t += 256) sd[t] = cG[t];
    __syncthreads();
    float mn = 1e30f, mx = -1e30f;
    for (int t = tid; t < T_ - 1; t += 256){ float vv = sd[t]; mn = fminf(mn, vv); mx = fmaxf(mx, vv); }
    #pragma unroll
    for (int m = 32; m >= 1; m >>= 1){
      mn = fminf(mn, __shfl_xor(mn, m, 64));
      mx = fmaxf(mx, __shfl_xor(mx, m, 64));
    }
    if (lane == 0){ smin[w] = mn; smax[w] = mx; }
    __syncthreads();
    mn = fminf(fminf(smin[0], smin[1]), fminf(smin[2], smin[3]));
    mx = fmaxf(fmaxf(smax[0], smax[1]), fmaxf(smax[2], smax[3]));
    float inv = 1.0f / (mx - mn);
    for (int t = tid; t < T_ - 1; t += 256)
      sd[t] = 1.0f - (sd[t] - mn) * inv;
    __syncthreads();
    for (int t = tid; t < T_; t += 256){
      float vv;
      if (t == 0) vv = 1.0f;
      else {
        int i = t - 1;                          // index into d (length T-1)
        if (i < 2 || i > T_ - 4) vv = 0.0f;     // p2[:, :2] = 0, p2[:, -2:] = 0
        else {
          float d0 = sd[i];
          float p2 = fminf(fmaxf(d0 - sd[i + 2], 0.0f), fmaxf(d0 - sd[i - 2], 0.0f));
          vv = tanhf(1e7f * p2);
        }
      }
      sb[t] = vv;
    }
    __syncthreads();
    float loc[8]; float sum8 = 0.0f;
    #pragma unroll
    for (int j = 0; j < 8; ++j){ sum8 += sb[8 * tid + j]; loc[j] = sum8; }
    float v = sum8;
    #pragma unroll
    for (int off = 1; off < 64; off <<= 1){
      float n = __shfl_up(v, (unsigned)off, 64);
      if (lane >= off) v += n;
    }
    if (lane == 63) swv[w] = v;
    __syncthreads();
    float wpre = 0.0f;
    for (int i = 0; i < w; ++i) wpre += swv[i];
    float excl = wpre + v - sum8;
    #pragma unroll
    for (int j = 0; j < 8; ++j) bcg[b * T_ + 8 * tid + j] = excl + loc[j];
    if (tid == 255) numfrg[b] = excl + sum8;
  }
  grid.sync();

  // ---- phase 3: pool (r8 k_pool body). Block: batch blk>>8, s in [(blk&255)*8, +8).
  {
    int b = blk >> 8;
    int sbase = (blk & 255) * 8;
    const float4* src4 = (const float4*)(bcg + b * T_);
    float4* dst4 = (float4*)sd;
    #pragma unroll
    for (int i = 0; i < T_ / 4 / 256; ++i) dst4[tid + i * 256] = src4[tid + i * 256];
    __syncthreads();
    float numfr = numfrg[b];
    const float4* f4 = (const float4*)(fr + (size_t)b * T_ * D_);
    #pragma unroll
    for (int k = 0; k < 2; ++k){
      int s = sbase + w * 2 + k;
      float4 acc = {0.0f, 0.0f, 0.0f, 0.0f};
      if ((float)(s + 1) <= numfr){
        float cc = (float)(s + 1);
        float lov = cc - 1.0f, hiv = cc + 1.0f;
        int lo = 0, hi = T_;
        while (lo < hi){ int mid = (lo + hi) >> 1; if (sd[mid] < lov) lo = mid + 1; else hi = mid; }
        float scol = 0.0f;
        for (int t = lo; t < T_ && sd[t] <= hiv; ++t)
          scol += 1.0f - tanhf(10.0f * fabsf(cc - sd[t]));
        for (int t = lo; t < T_ && sd[t] <= hiv; ++t){
          float u = tanhf(10.0f * fabsf(cc - sd[t]));
          float m = (1.0f - u) / (scol + u);
          float4 f = f4[(size_t)t * 64 + lane];
          acc.x += m * f.x; acc.y += m * f.y; acc.z += m * f.z; acc.w += m * f.w;
        }
      }
      ((float4*)out)[((size_t)b * S_ + s) * 64 + lane] = acc;
    }
  }
}

extern "C" void kernel_launch(void* const* d_in, const int* in_sizes, int n_in,
                              void* d_out, int out_size, void* d_ws, size_t ws_size,
                              hipStream_t stream) {
  const float* frames = (const float*)d_in[0];
  float* ws = (float*)d_ws;
  float* cosg   = ws;                    // B*T
  float* bcg    = ws + B_ * T_;          // B*T
  float* numfrg = ws + 2 * B_ * T_;      // B
  float* out = (float*)d_out;

  void* args[] = {(void*)&frames, (void*)&cosg, (void*)&bcg, (void*)&numfrg, (void*)&out};
  hipLaunchCooperativeKernel((void*)k_all, dim3(NBLK), dim3(256), args, 0, stream);
}

// Round 13
// 35.270 us; speedup vs baseline: 10.8356x; 10.8356x over previous
//
#include <hip/hip_runtime.h>
#include <hip/hip_bf16.h>

#define B_ 8
#define T_ 2048
#define D_ 256
#define S_ 2048

// Kernel 1: cos[b,t] for t in [0,T-2]. One wave per 8 consecutive rows with
// register row-reuse: 9 row-loads per 8 cos values; nsq of each row reduced
// once and carried (bit-identical math to the r8 per-pair version).
__global__ __launch_bounds__(256) void k_dotcos(const float* __restrict__ fr,
                                                float* __restrict__ cosg){
  int lane = threadIdx.x & 63;
  int w = threadIdx.x >> 6;
  long p0 = ((long)blockIdx.x * 4 + w) * 8;   // first row of this wave's chunk
  const float4* f4 = (const float4*)fr;
  float4 a = f4[p0 * 64 + lane];
  float na = a.x*a.x + a.y*a.y + a.z*a.z + a.w*a.w;
  #pragma unroll
  for (int m = 32; m >= 1; m >>= 1) na += __shfl_xor(na, m, 64);
  int rmax = (p0 + 8 <= (long)B_ * T_ - 1) ? 8 : 7;   // avoid OOB load on final chunk
  for (int r = 1; r <= rmax; ++r){
    long p = p0 + r;
    float4 c = f4[p * 64 + lane];
    float nc = c.x*c.x + c.y*c.y + c.z*c.z + c.w*c.w;
    float dt = a.x*c.x + a.y*c.y + a.z*c.z + a.w*c.w;
    #pragma unroll
    for (int m = 32; m >= 1; m >>= 1){
      nc += __shfl_xor(nc, m, 64);
      dt += __shfl_xor(dt, m, 64);
    }
    int t = (int)((p - 1) & (T_ - 1));
    if (lane == 0 && t != T_ - 1)
      cosg[p - 1] = dt / fmaxf(sqrtf(na) * sqrtf(nc), 1e-6f);
    a = c; na = nc;
  }
}

// Kernel 2: per batch, f32, fully parallel: minmax(cos) -> d -> p2 -> b ->
// block scan (per-thread 8 elems + wave shfl scan + cross-wave LDS).
__global__ __launch_bounds__(256) void k_boundary(const float* __restrict__ cosg,
                                                  float* __restrict__ bcg,
                                                  float* __restrict__ numfrg){
  __shared__ float sd[T_];
  __shared__ float sb[T_];
  __shared__ float smin[4], smax[4], swv[4];
  int b = blockIdx.x, tid = threadIdx.x;
  int lane = tid & 63, w = tid >> 6;
  const float* cG = cosg + b * T_;
  for (int t = tid; t < T_ - 1; t += 256) sd[t] = cG[t];
  __syncthreads();
  float mn = 1e30f, mx = -1e30f;
  for (int t = tid; t < T_ - 1; t += 256){ float v = sd[t]; mn = fminf(mn, v); mx = fmaxf(mx, v); }
  #pragma unroll
  for (int m = 32; m >= 1; m >>= 1){
    mn = fminf(mn, __shfl_xor(mn, m, 64));
    mx = fmaxf(mx, __shfl_xor(mx, m, 64));
  }
  if (lane == 0){ smin[w] = mn; smax[w] = mx; }
  __syncthreads();
  mn = fminf(fminf(smin[0], smin[1]), fminf(smin[2], smin[3]));
  mx = fmaxf(fmaxf(smax[0], smax[1]), fmaxf(smax[2], smax[3]));
  float inv = 1.0f / (mx - mn);
  for (int t = tid; t < T_ - 1; t += 256)
    sd[t] = 1.0f - (sd[t] - mn) * inv;
  __syncthreads();
  for (int t = tid; t < T_; t += 256){
    float v;
    if (t == 0) v = 1.0f;
    else {
      int i = t - 1;                          // index into d (length T-1)
      if (i < 2 || i > T_ - 4) v = 0.0f;      // p2[:, :2] = 0, p2[:, -2:] = 0
      else {
        float d0 = sd[i];
        float p2 = fminf(fmaxf(d0 - sd[i + 2], 0.0f), fmaxf(d0 - sd[i - 2], 0.0f));
        v = tanhf(1e7f * p2);
      }
    }
    sb[t] = v;
  }
  __syncthreads();
  float loc[8]; float s = 0.0f;
  #pragma unroll
  for (int j = 0; j < 8; ++j){ s += sb[8 * tid + j]; loc[j] = s; }
  float v = s;
  #pragma unroll
  for (int off = 1; off < 64; off <<= 1){
    float n = __shfl_up(v, (unsigned)off, 64);
    if (lane >= off) v += n;
  }
  if (lane == 63) swv[w] = v;
  __syncthreads();
  float wpre = 0.0f;
  for (int i = 0; i < w; ++i) wpre += swv[i];
  float excl = wpre + v - s;
  #pragma unroll
  for (int j = 0; j < 8; ++j) bcg[b * T_ + 8 * tid + j] = excl + loc[j];
  if (tid == 255) numfrg[b] = excl + s;
}

// Kernel 3 (fused colsum+pool): one WAVE per s. bc monotone => only t with
// bc[t] in [cc-1, cc+1] contribute > 4.2e-9. Pass 1: scol = sum(res).
// Pass 2: acc += m * frames[t], m = (1-u)/(scol+u). Lanes hold float4 of D.
// Blocks whose 4 s are all invalid skip bc staging and just write zeros.
__global__ __launch_bounds__(256) void k_pool(const float* __restrict__ fr,
                                              const float* __restrict__ bcg,
                                              const float* __restrict__ numfrg,
                                              float* __restrict__ out){
  __shared__ float sbc[T_];
  int tid = threadIdx.x;
  int lane = tid & 63, w = tid >> 6;
  int b = blockIdx.y;
  int s = blockIdx.x * 4 + w;
  float numfr = numfrg[b];
  if ((float)(blockIdx.x * 4 + 1) > numfr){
    // all 4 s invalid: ref res underflows to 0 in f32 -> exact zeros.
    float4 z = {0.0f, 0.0f, 0.0f, 0.0f};
    ((float4*)out)[((size_t)b * S_ + s) * 64 + lane] = z;
    return;
  }
  const float4* src4 = (const float4*)(bcg + b * T_);
  float4* dst4 = (float4*)sbc;
  #pragma unroll
  for (int i = 0; i < T_ / 4 / 256; ++i) dst4[tid + i * 256] = src4[tid + i * 256];
  __syncthreads();
  float4 acc = {0.0f, 0.0f, 0.0f, 0.0f};
  if ((float)(s + 1) <= numfr){
    float cc = (float)(s + 1);
    float lov = cc - 1.0f, hiv = cc + 1.0f;
    int lo = 0, hi = T_;
    while (lo < hi){ int mid = (lo + hi) >> 1; if (sbc[mid] < lov) lo = mid + 1; else hi = mid; }
    float scol = 0.0f;
    for (int t = lo; t < T_ && sbc[t] <= hiv; ++t)
      scol += 1.0f - tanhf(10.0f * fabsf(cc - sbc[t]));
    const float4* f4 = (const float4*)(fr + (size_t)b * T_ * D_);
    for (int t = lo; t < T_ && sbc[t] <= hiv; ++t){
      float u = tanhf(10.0f * fabsf(cc - sbc[t]));
      float m = (1.0f - u) / (scol + u);
      float4 f = f4[(size_t)t * 64 + lane];
      acc.x += m * f.x; acc.y += m * f.y; acc.z += m * f.z; acc.w += m * f.w;
    }
  }
  ((float4*)out)[((size_t)b * S_ + s) * 64 + lane] = acc;
}

extern "C" void kernel_launch(void* const* d_in, const int* in_sizes, int n_in,
                              void* d_out, int out_size, void* d_ws, size_t ws_size,
                              hipStream_t stream) {
  const float* frames = (const float*)d_in[0];
  float* ws = (float*)d_ws;
  float* cosg   = ws;                    // B*T
  float* bcg    = ws + B_ * T_;          // B*T
  float* numfrg = ws + 2 * B_ * T_;      // B
  float* out = (float*)d_out;

  k_dotcos<<<B_ * T_ / 32, 256, 0, stream>>>(frames, cosg);
  k_boundary<<<B_, 256, 0, stream>>>(cosg, bcg, numfrg);
  k_pool<<<dim3(S_ / 4, B_), 256, 0, stream>>>(frames, bcg, numfrg, out);
}

// Round 14
// 29.813 us; speedup vs baseline: 12.8191x; 1.1830x over previous
//
#include <hip/hip_runtime.h>
#include <hip/hip_bf16.h>

#define B_ 8
#define T_ 2048
#define D_ 256
#define S_ 2048

// Kernel 1: cos[b,t] = <f[t],f[t+1]> / max(|f[t]||f[t+1]|, 1e-6), t in [0,T-2].
// One wave per row t (4096 blocks -> max TLP; all inputs L2/LLC-resident).
__global__ __launch_bounds__(256) void k_dotcos(const float* __restrict__ fr,
                                                float* __restrict__ cosg){
  int lane = threadIdx.x & 63;
  int w = threadIdx.x >> 6;
  int p = blockIdx.x * 4 + w;                 // p = b*T + t
  int t = p & (T_ - 1);
  const float4* f4 = (const float4*)fr;
  float4 a = f4[(size_t)p * 64 + lane];
  float na = a.x*a.x + a.y*a.y + a.z*a.z + a.w*a.w;
  float nc = 0.0f, dt = 0.0f;
  if (t < T_ - 1){
    float4 c = f4[(size_t)(p + 1) * 64 + lane];
    nc = c.x*c.x + c.y*c.y + c.z*c.z + c.w*c.w;
    dt = a.x*c.x + a.y*c.y + a.z*c.z + a.w*c.w;
  }
  #pragma unroll
  for (int m = 32; m >= 1; m >>= 1){
    na += __shfl_xor(na, m, 64);
    nc += __shfl_xor(nc, m, 64);
    dt += __shfl_xor(dt, m, 64);
  }
  if (lane == 0 && t < T_ - 1)
    cosg[p] = dt / fmaxf(sqrtf(na) * sqrtf(nc), 1e-6f);
}

// Kernel 2: per batch: minmax(cos) -> d -> p2 -> b -> block scan -> bc,
// then per-s window starts lo_tbl[s] = first t with bc[t] >= s+1-1
// (binary search in LDS, 8 searches/thread). Op-order bit-identical to r8.
__global__ __launch_bounds__(256) void k_boundary(const float* __restrict__ cosg,
                                                  float* __restrict__ bcg,
                                                  float* __restrict__ numfrg,
                                                  int* __restrict__ lotbl){
  __shared__ float sd[T_];
  __shared__ float sb[T_];
  __shared__ float smin[4], smax[4], swv[4], snum;
  int b = blockIdx.x, tid = threadIdx.x;
  int lane = tid & 63, w = tid >> 6;
  const float* cG = cosg + b * T_;
  for (int t = tid; t < T_ - 1; t += 256) sd[t] = cG[t];
  __syncthreads();
  float mn = 1e30f, mx = -1e30f;
  for (int t = tid; t < T_ - 1; t += 256){ float v = sd[t]; mn = fminf(mn, v); mx = fmaxf(mx, v); }
  #pragma unroll
  for (int m = 32; m >= 1; m >>= 1){
    mn = fminf(mn, __shfl_xor(mn, m, 64));
    mx = fmaxf(mx, __shfl_xor(mx, m, 64));
  }
  if (lane == 0){ smin[w] = mn; smax[w] = mx; }
  __syncthreads();
  mn = fminf(fminf(smin[0], smin[1]), fminf(smin[2], smin[3]));
  mx = fmaxf(fmaxf(smax[0], smax[1]), fmaxf(smax[2], smax[3]));
  float inv = 1.0f / (mx - mn);
  for (int t = tid; t < T_ - 1; t += 256)
    sd[t] = 1.0f - (sd[t] - mn) * inv;
  __syncthreads();
  for (int t = tid; t < T_; t += 256){
    float v;
    if (t == 0) v = 1.0f;
    else {
      int i = t - 1;                          // index into d (length T-1)
      if (i < 2 || i > T_ - 4) v = 0.0f;      // p2[:, :2] = 0, p2[:, -2:] = 0
      else {
        float d0 = sd[i];
        float p2 = fminf(fmaxf(d0 - sd[i + 2], 0.0f), fmaxf(d0 - sd[i - 2], 0.0f));
        v = tanhf(1e7f * p2);
      }
    }
    sb[t] = v;
  }
  __syncthreads();
  float loc[8]; float s = 0.0f;
  #pragma unroll
  for (int j = 0; j < 8; ++j){ s += sb[8 * tid + j]; loc[j] = s; }
  float v = s;
  #pragma unroll
  for (int off = 1; off < 64; off <<= 1){
    float n = __shfl_up(v, (unsigned)off, 64);
    if (lane >= off) v += n;
  }
  if (lane == 63) swv[w] = v;
  __syncthreads();
  float wpre = 0.0f;
  for (int i = 0; i < w; ++i) wpre += swv[i];
  float excl = wpre + v - s;
  #pragma unroll
  for (int j = 0; j < 8; ++j){
    float bcv = excl + loc[j];
    sd[8 * tid + j] = bcv;                    // bc into LDS for the searches
    bcg[b * T_ + 8 * tid + j] = bcv;
  }
  if (tid == 255){ numfrg[b] = excl + s; snum = excl + s; }
  __syncthreads();
  float nf = snum;
  for (int si = tid; si < S_; si += 256){
    int lo = T_;
    float cc = (float)(si + 1);
    if (cc <= nf){
      float lov = cc - 1.0f;
      lo = 0; int hi = T_;
      while (lo < hi){ int mid = (lo + hi) >> 1; if (sd[mid] < lov) lo = mid + 1; else hi = mid; }
    }
    lotbl[b * S_ + si] = lo;
  }
}

// Kernel 3: one WAVE per s, LDS-free. Window start from lo_tbl; lane-parallel
// window (lane j owns t=base+j): scol via wave reduce (r10-proven order), then
// fma sweep with shfl-broadcast m. Blocks with all-invalid s write zeros.
__global__ __launch_bounds__(256) void k_pool(const float* __restrict__ fr,
                                              const float* __restrict__ bcg,
                                              const float* __restrict__ numfrg,
                                              const int* __restrict__ lotbl,
                                              float* __restrict__ out){
  int tid = threadIdx.x;
  int lane = tid & 63, w = tid >> 6;
  int b = blockIdx.y;
  int s = blockIdx.x * 4 + w;
  float numfr = numfrg[b];
  float4 acc = {0.0f, 0.0f, 0.0f, 0.0f};
  if ((float)(blockIdx.x * 4 + 1) <= numfr && (float)(s + 1) <= numfr){
    float cc = (float)(s + 1);
    float hiv = cc + 1.0f;
    int lo = lotbl[b * S_ + s];
    const float* bcb = bcg + b * T_;
    const float4* f4 = (const float4*)(fr + (size_t)b * T_ * D_);
    // pass 1: scol (all t >= lo have bc >= cc-1 by lo_tbl construction)
    float scol = 0.0f;
    for (int base = lo; base < T_; base += 64){
      int t = base + lane;
      float bcv = (t < T_) ? bcb[t] : 1e30f;
      bool in = bcv <= hiv;
      float r = in ? 1.0f - tanhf(10.0f * fabsf(cc - bcv)) : 0.0f;
      #pragma unroll
      for (int m = 32; m >= 1; m >>= 1) r += __shfl_xor(r, m, 64);
      scol += r;
      if (__popcll(__ballot(in)) < 64) break;
    }
    // pass 2: acc += m_t * frames[t]
    for (int base = lo; base < T_; base += 64){
      int t = base + lane;
      float bcv = (t < T_) ? bcb[t] : 1e30f;
      bool in = bcv <= hiv;
      float mval = 0.0f;
      if (in){
        float u = tanhf(10.0f * fabsf(cc - bcv));
        mval = (1.0f - u) / (scol + u);
      }
      int cnt = __popcll(__ballot(in));
      for (int j = 0; j < cnt; ++j){
        float mj = __shfl(mval, j, 64);
        float4 f = f4[(size_t)(base + j) * 64 + lane];
        acc.x += mj * f.x; acc.y += mj * f.y; acc.z += mj * f.z; acc.w += mj * f.w;
      }
      if (cnt < 64) break;
    }
  }
  ((float4*)out)[((size_t)b * S_ + s) * 64 + lane] = acc;
}

extern "C" void kernel_launch(void* const* d_in, const int* in_sizes, int n_in,
                              void* d_out, int out_size, void* d_ws, size_t ws_size,
                              hipStream_t stream) {
  const float* frames = (const float*)d_in[0];
  float* ws = (float*)d_ws;
  float* cosg   = ws;                    // B*T
  float* bcg    = ws + B_ * T_;          // B*T
  float* numfrg = ws + 2 * B_ * T_;      // B
  int*   lotbl  = (int*)(ws + 2 * B_ * T_ + 64);   // B*S ints
  float* out = (float*)d_out;

  k_dotcos<<<B_ * T_ / 4, 256, 0, stream>>>(frames, cosg);
  k_boundary<<<B_, 256, 0, stream>>>(cosg, bcg, numfrg, lotbl);
  k_pool<<<dim3(S_ / 4, B_), 256, 0, stream>>>(frames, bcg, numfrg, lotbl, out);
}